// Round 1
// baseline (261.286 us; speedup 1.0000x reference)
//
#include <hip/hip_runtime.h>
#include <climits>
#include <cstdint>

// ---------------- problem constants (mirror reference) ----------------
constexpr int kB  = 64;
constexpr int kG0 = 19, kG1 = 38, kG2 = 76;
constexpr int kN0 = 3 * kG0 * kG0;   // 1083
constexpr int kN1 = 3 * kG1 * kG1;   // 4332
constexpr int kN2 = 3 * kG2 * kG2;   // 17328
constexpr int kN  = kN0 + kN1 + kN2; // 22743
constexpr int kNP = kN + 1;          // padded row stride (22744): rows 16B-aligned for uint4
constexpr int kM  = 256;             // M_CAND
constexpr int kTopK = 8;
constexpr float kNEG = -1e9f;
constexpr int kHB = 4096;            // 12-bit score-histogram bins per image

// per-image tiles of 256 cells per level: ceil(1083/256)=5, ceil(4332/256)=17, ceil(17328/256)=68
constexpr int kT0 = 5, kT1 = 17, kT2 = 68;
constexpr int kTilesPerImg = kT0 + kT1 + kT2;  // 90
constexpr int kGridScore = 1920;               // pipeline: 1920 blocks x 3 tiles = 5760
constexpr int kTilesPerBlk = 3;

__constant__ float c_anchors[3][3][2] = {
    {{116.f, 90.f}, {156.f, 198.f}, {373.f, 326.f}},
    {{30.f, 61.f},  {62.f, 45.f},   {59.f, 119.f}},
    {{10.f, 13.f},  {16.f, 30.f},   {33.f, 23.f}},
};

typedef float f4_t __attribute__((ext_vector_type(4)));

// fast transcendentals: v_exp_f32 + v_rcp_f32 (~2-4 ULP; thresholds have huge slack)
__device__ __forceinline__ float fexpf(float x) { return __expf(x); }
__device__ __forceinline__ float frcpf(float x) { return __builtin_amdgcn_rcpf(x); }
__device__ __forceinline__ float fsigm(float x) { return frcpf(1.0f + __expf(-x)); }

// non-temporal loads (no cache allocation -> doesn't evict the harness's dirty
// poison lines from L3; the suspected cause of the ~67us score floor)
__device__ __forceinline__ float2 nt_load_f2(const float2* p) {
  unsigned long long v = __builtin_nontemporal_load((const unsigned long long*)p);
  union { unsigned long long u; float2 f; } c; c.u = v; return c.f;
}
__device__ __forceinline__ f4_t nt_load_f4(const f4_t* p) {
  return __builtin_nontemporal_load(p);
}

// order-preserving float->uint key (ascending). NEG maps below every score>=0.
__device__ __forceinline__ unsigned score_to_key(float s) {
  unsigned fb = __float_as_uint(s);
  unsigned m = (fb & 0x80000000u) ? 0xFFFFFFFFu : 0x80000000u;
  return fb ^ m;
}
__device__ __forceinline__ float key_to_score(unsigned k) {
  unsigned fb = (k & 0x80000000u) ? (k ^ 0x80000000u) : ~k;
  return __uint_as_float(fb);
}

// flat candidate index n -> cell pointer + (level, anchor, row i, col j, stride)
__device__ __forceinline__ const float* cell_ptr(
    const float* p0, const float* p1, const float* p2, int b, int n,
    int& lvl, int& a, int& gi, int& gj, float& stride) {
  const float* src; int G, m;
  if (n < kN0)            { src = p0; G = kG0; lvl = 0; m = n;             stride = 32.f; }
  else if (n < kN0 + kN1) { src = p1; G = kG1; lvl = 1; m = n - kN0;       stride = 16.f; }
  else                    { src = p2; G = kG2; lvl = 2; m = n - kN0 - kN1; stride = 8.f; }
  int gg = G * G;
  a = m / gg;
  int r = m - a * gg;
  gi = r / G;
  gj = r - gi * G;
  return src + (size_t)((((b * 3 + a) * G + gi) * G + gj)) * 26;
}

// ---------------- wave (64-lane) helpers ----------------
__device__ __forceinline__ void waveArgmax(float& v, int& i) {
  #pragma unroll
  for (int off = 1; off < 64; off <<= 1) {
    float ov = __shfl_xor(v, off);
    int oi = __shfl_xor(i, off);
    if (ov > v || (ov == v && oi < i)) { v = ov; i = oi; }
  }
}
__device__ __forceinline__ float waveMax(float v) {
  #pragma unroll
  for (int off = 1; off < 64; off <<= 1) v = fmaxf(v, __shfl_xor(v, off));
  return v;
}
__device__ __forceinline__ float sel4f(const float a[4], int q) {
  float r = a[0];
  r = (q == 1) ? a[1] : r;
  r = (q == 2) ? a[2] : r;
  r = (q == 3) ? a[3] : r;
  return r;
}
__device__ __forceinline__ int sel4i(const int a[4], int q) {
  int r = a[0];
  r = (q == 1) ? a[1] : r;
  r = (q == 2) ? a[2] : r;
  r = (q == 3) ? a[3] : r;
  return r;
}

// ---------------- kernel 1: pipelined tiled score -> keys + per-image histogram --------
// 1920 blocks x 3 tiles, double-buffered LDS. Staging = coalesced non-temporal loads into
// registers (next tile) overlapped with compute (current tile); regs->LDS after.
// NEW vs prev version:
//  (a) 16B NT dwordx4 staging where the tile base is 16B-aligned (all tiles except
//      level-0 tiles of odd images: 94.5% of bytes); float2 fallback otherwise.
//  (b) builds gHist[b][key>>20] with scattered global atomics (~3.4k/image valid
//      candidates) -> select kernel no longer needs its pass-1 global sweep.
__global__ __launch_bounds__(256) void score_kernel(
    const float* __restrict__ p0, const float* __restrict__ p1, const float* __restrict__ p2,
    unsigned* __restrict__ keys, int* __restrict__ gHist)
{
  __shared__ float lds[2][256 * 26];   // 2 x 26624 B

  int t = threadIdx.x;

  // wave-uniform tile parameters for the 3 tiles of this block
  const float* gb[kTilesPerBlk];
  int nc[kTilesPerBlk], nfl[kTilesPerBlk], n0[kTilesPerBlk], bb[kTilesPerBlk];
  bool al16[kTilesPerBlk];
  #pragma unroll
  for (int j = 0; j < kTilesPerBlk; ++j) {
    int tileId = (int)blockIdx.x + j * kGridScore;
    int b = tileId / kTilesPerImg;
    int r = tileId - b * kTilesPerImg;
    const float* slab; int NL, lvlOff, tile;
    if (r < kT0)            { slab = p0; NL = kN0; lvlOff = 0;         tile = r; }
    else if (r < kT0 + kT1) { slab = p1; NL = kN1; lvlOff = kN0;       tile = r - kT0; }
    else                    { slab = p2; NL = kN2; lvlOff = kN0 + kN1; tile = r - kT0 - kT1; }
    int cellBase = tile * 256;
    nc[j]  = min(256, NL - cellBase);
    nfl[j] = nc[j] * 26;
    gb[j]  = slab + ((size_t)b * NL + cellBase) * 26;
    al16[j] = ((((uintptr_t)gb[j]) & 15) == 0);
    n0[j] = lvlOff + cellBase;
    bb[j] = b;
  }

  // staging registers: 28 floats covers 7 dwordx4 (aligned) or 13 dwordx2+pad (unaligned)
  float sreg[28];

  auto stageLoad = [&](int j) {
    const float* g = gb[j]; int nf = nfl[j];
    if (al16[j]) {
      int n4 = nf >> 2;
      #pragma unroll
      for (int k = 0; k < 7; ++k) {
        int i = t + k * 256;
        if (i < n4) {
          f4_t v = nt_load_f4((const f4_t*)g + i);
          sreg[4*k] = v[0]; sreg[4*k+1] = v[1]; sreg[4*k+2] = v[2]; sreg[4*k+3] = v[3];
        }
      }
      if ((nf & 3) && t == 0) {            // 2-float tail (odd cell count tiles)
        float2 v = nt_load_f2((const float2*)g + (n4 << 1));
        sreg[26] = v.x; sreg[27] = v.y;
      }
    } else {
      int n2 = nf >> 1;                    // nf always even
      #pragma unroll
      for (int k = 0; k < 13; ++k) {
        int i = t + k * 256;
        if (i < n2) {
          float2 v = nt_load_f2((const float2*)g + i);
          sreg[2*k] = v.x; sreg[2*k+1] = v.y;
        }
      }
    }
  };
  auto stageWrite = [&](int j, float* dst) {
    int nf = nfl[j];
    if (al16[j]) {
      int n4 = nf >> 2;
      f4_t* d4 = (f4_t*)dst;
      #pragma unroll
      for (int k = 0; k < 7; ++k) {
        int i = t + k * 256;
        if (i < n4) {
          f4_t w; w[0] = sreg[4*k]; w[1] = sreg[4*k+1]; w[2] = sreg[4*k+2]; w[3] = sreg[4*k+3];
          d4[i] = w;
        }
      }
      if ((nf & 3) && t == 0) {
        float2* d2 = (float2*)dst;
        float2 w; w.x = sreg[26]; w.y = sreg[27];
        d2[n4 << 1] = w;
      }
    } else {
      int n2 = nf >> 1;
      float2* d2 = (float2*)dst;
      #pragma unroll
      for (int k = 0; k < 13; ++k) {
        int i = t + k * 256;
        if (i < n2) { float2 w; w.x = sreg[2*k]; w.y = sreg[2*k+1]; d2[i] = w; }
      }
    }
  };

  // prologue: tile 0 -> regs -> LDS buf 0
  stageLoad(0);
  stageWrite(0, &lds[0][0]);

  #pragma unroll
  for (int j = 0; j < kTilesPerBlk; ++j) {
    __syncthreads();   // LDS writes of buf j&1 visible; prev compute done

    // issue NT loads for tile j+1 (in flight during compute below)
    if (j + 1 < kTilesPerBlk) stageLoad(j + 1);

    // compute tile j from LDS buf j&1
    int curNc = nc[j], curN0 = n0[j], curB = bb[j];
    if (t < curNc) {
      const float2* c2 = (const float2*)&lds[j & 1][t * 26]; // stride-26: 2-way alias (free)
      float2 ol = c2[2];                  // channels 4,5
      float obj = fsigm(ol.x);
      float loc = fsigm(ol.y);
      float tch[20];
      #pragma unroll
      for (int q = 0; q < 10; ++q) { float2 v = c2[3 + q]; tch[2*q] = v.x; tch[2*q+1] = v.y; }
      float lm = tch[0];
      #pragma unroll
      for (int c = 1; c < 20; ++c) lm = fmaxf(lm, tch[c]);
      float se = 0.f;
      #pragma unroll
      for (int c = 0; c < 20; ++c) se += fexpf(tch[c] - lm);
      float cls_conf = frcpf(se);         // max of softmax == exp(0)/sum
      float conf = obj * cls_conf;
      float masked = (obj >= 0.6f && loc >= 0.5f && conf >= 0.05f)
                     ? sqrtf(conf) * sqrtf(loc) : kNEG;  // (obj*cc)^.5 * loc^.5
      unsigned key = score_to_key(masked);
      keys[(size_t)curB * kNP + curN0 + t] = key;        // coalesced u32 store
      // free histogram build: VALU/atomic issue hides under the BW-bound staging
      if (key & 0x80000000u) atomicAdd(&gHist[curB * kHB + (int)(key >> 20)], 1);
    }

    // regs -> other LDS buffer (after compute; next iter's barrier publishes it)
    if (j + 1 < kTilesPerBlk) stageWrite(j + 1, &lds[(j + 1) & 1][0]);
  }
}

// ---------------- parallel threshold-bin finder ----------------
// Largest bin B with suffix_count(B) >= needed; cumAbove = count strictly above B; total = all.
// All 512 threads participate uniformly.
__device__ __forceinline__ void findThresholdBin(
    const int* hist, int NB, int needed,
    int& outB, int& outCumAbove, int& outTotal,
    int* shWave, int* shOut)
{
  int tid = threadIdx.x, lane = tid & 63, w = tid >> 6;
  if (tid == 0) { shOut[0] = -1; shOut[1] = 0; }
  int ipt = (NB + 511) / 512;
  int base = tid * ipt;
  int csum = 0;
  for (int i = 0; i < ipt; ++i) { int bn = base + i; if (bn < NB) csum += hist[bn]; }
  // inclusive suffix scan within wave (lane l gets sum over lanes >= l)
  int v = csum;
  #pragma unroll
  for (int off = 1; off < 64; off <<= 1) {
    int tv = __shfl_down(v, off);
    if (lane + off < 64) v += tv;
  }
  if (lane == 0) shWave[w] = v;   // wave total
  __syncthreads();
  int above = 0, total = 0;
  #pragma unroll
  for (int q = 0; q < 8; ++q) {
    int wt = shWave[q];
    total += wt;
    if (q > w) above += wt;
  }
  int S = v + above;              // suffix count including own chunk
  if (S >= needed && S - csum < needed) {   // exactly one thread's chunk crosses
    int running = S - csum;
    for (int i = ipt - 1; i >= 0; --i) {
      int bn = base + i; if (bn >= NB) continue;
      int c = hist[bn];
      if (running + c >= needed) { shOut[0] = bn; shOut[1] = running; break; }
      running += c;
    }
  }
  __syncthreads();
  outB = shOut[0]; outCumAbove = shOut[1]; outTotal = total;
  __syncthreads();
}

constexpr int kNV4 = kN / 4;        // 5685 full uint4 per image row (covers 22740)
constexpr int kTail = kN - kNV4*4;  // 3 scalar tail elements

// ---------------- kernel 2: single-sweep select (prebuilt hist) + soft-NMS (wave 0) -----
// Threshold bin comes from gHist (built by kernel 1) -> no histogram sweep. One global
// sweep gathers winners (>bin) and pools bin ties in LDS; tie refinement (key bits 19:8,
// 7:0, then smallest index) runs entirely on the LDS pool. Then wave 0 runs the
// register-resident NMS. Candidate set + scores bit-identical to the 4-sweep version.
__global__ __launch_bounds__(512) void select_nms_kernel(
    const unsigned* __restrict__ keys, const int* __restrict__ gHist,
    const float* __restrict__ p0, const float* __restrict__ p1, const float* __restrict__ p2,
    float* __restrict__ out)
{
  int b = blockIdx.x, tid = threadIdx.x;
  const unsigned* kk = keys + (size_t)b * kNP;
  const uint4* kk4 = (const uint4*)kk;      // row base b*kNP*4 = b*90976 (16-aligned)
  const unsigned keyNEG = score_to_key(kNEG);

  constexpr int kPool = 4096;
  __shared__ int hist[kHB];                 // gHist copy, then reused as mid/low hist
  __shared__ int shWave[8], shOut[2];
  __shared__ int ciL[kM];
  __shared__ unsigned ckL[kM];
  __shared__ unsigned pk[kPool];            // bin-B tie pool: keys
  __shared__ int piA[kPool];                //                 original indices
  __shared__ int eqI[256];                  // exact-key tie indices (fast path)
  __shared__ int sCnt, eqCnt, sTie;

  // ---- threshold bin from prebuilt histogram (no sweep) ----
  for (int i = tid; i < kHB; i += 512) hist[i] = gHist[(size_t)b * kHB + i];
  __syncthreads();
  int B, cumAbove1, total1;
  findThresholdBin(hist, kHB, kM, B, cumAbove1, total1, shWave, shOut);

  if (tid == 0) { sCnt = 0; eqCnt = 0; sTie = 0; }
  // re-zero for the mid-bits histogram built during the sweep
  for (int i = tid; i < kHB; i += 512) hist[i] = 0;
  __syncthreads();

  if (total1 < kM) {
    // ---- fewer than 256 valid: gather them all, pad with dummies ----
    for (int x = tid; x < kNV4; x += 512) {
      uint4 v = kk4[x];
      int i4 = x * 4;
      unsigned kv[4] = {v.x, v.y, v.z, v.w};
      #pragma unroll
      for (int e = 0; e < 4; ++e) {
        unsigned k = kv[e];
        if (k & 0x80000000u) { int p = atomicAdd(&sCnt, 1); ciL[p] = i4 + e; ckL[p] = k; }
      }
    }
    if (tid < kTail) {
      int x = kNV4 * 4 + tid;
      unsigned k = kk[x];
      if (k & 0x80000000u) { int p = atomicAdd(&sCnt, 1); ciL[p] = x; ckL[p] = k; }
    }
    __syncthreads();
    // NEG filler candidates: never kept, never picked, never influence others
    if (tid >= total1 && tid < kM) { ciL[tid] = -1; ckL[tid] = keyNEG; }
    __syncthreads();
  } else {
    unsigned uB = (unsigned)B;
    // ---- single sweep: gather hi>B winners; pool hi==B ties (+build mid-hist) ----
    for (int x = tid; x < kNV4; x += 512) {
      uint4 v = kk4[x];
      int i4 = x * 4;
      unsigned kv[4] = {v.x, v.y, v.z, v.w};
      #pragma unroll
      for (int e = 0; e < 4; ++e) {
        unsigned k = kv[e];
        unsigned hi = k >> 20;
        if (hi > uB) { int p = atomicAdd(&sCnt, 1); ciL[p] = i4 + e; ckL[p] = k; }
        else if (hi == uB) {
          int p = atomicAdd(&eqCnt, 1);
          if (p < kPool) { pk[p] = k; piA[p] = i4 + e; }
          atomicAdd(&hist[(k >> 8) & 0xFFFu], 1);
        }
      }
    }
    if (tid < kTail) {
      int x = kNV4 * 4 + tid;
      unsigned k = kk[x];
      unsigned hi = k >> 20;
      if (hi > uB) { int p = atomicAdd(&sCnt, 1); ciL[p] = x; ckL[p] = k; }
      else if (hi == uB) {
        int p = atomicAdd(&eqCnt, 1);
        if (p < kPool) { pk[p] = k; piA[p] = x; }
        atomicAdd(&hist[(k >> 8) & 0xFFFu], 1);
      }
    }
    __syncthreads();

    int needed = kM - cumAbove1;   // >= 1 by construction; sCnt == cumAbove1 here
    int pc = eqCnt;                // == exact bin-B population even if pool overflowed

    if (pc == needed) {
      // common-ish shortcut: whole bin fits exactly (pc <= 255 < kPool always here)
      if (tid < pc) { ciL[cumAbove1 + tid] = piA[tid]; ckL[cumAbove1 + tid] = pk[tid]; }
      __syncthreads();
    } else if (pc <= kPool) {
      // ---- LDS-resident refinement: bits 19:8, then 7:0, then smallest index ----
      int B2, cA2, tot2;
      findThresholdBin(hist, kHB, needed, B2, cA2, tot2, shWave, shOut);
      for (int i = tid; i < 256; i += 512) hist[i] = 0;   // reuse as low-8 hist
      __syncthreads();
      for (int i = tid; i < pc; i += 512) {
        unsigned k = pk[i];
        int mid = (int)((k >> 8) & 0xFFFu);
        if (mid > B2) { int p = atomicAdd(&sCnt, 1); ciL[p] = piA[i]; ckL[p] = k; }
        else if (mid == B2) atomicAdd(&hist[k & 0xFFu], 1);
      }
      __syncthreads();
      int needed3 = needed - cA2;
      int B3, cA3, tot3;
      findThresholdBin(hist, 256, needed3, B3, cA3, tot3, shWave, shOut);
      for (int i = tid; i < pc; i += 512) {
        unsigned k = pk[i];
        int mid = (int)((k >> 8) & 0xFFFu);
        if (mid == B2) {
          int lo = (int)(k & 0xFFu);
          if (lo > B3) { int p = atomicAdd(&sCnt, 1); ciL[p] = piA[i]; ckL[p] = k; }
          else if (lo == B3) { int p = atomicAdd(&sTie, 1); if (p < 256) eqI[p] = piA[i]; }
        }
      }
      __syncthreads();
      int needed4 = needed3 - cA3;   // >= 1
      unsigned exactKey = (uB << 20) | ((unsigned)B2 << 8) | (unsigned)B3;
      int nt_ = sTie;
      if (nt_ == needed4) {
        // typical: exact-threshold key unique (or exactly fills) -> direct append
        if (tid < needed4) {
          int base0 = kM - needed4;
          ciL[base0 + tid] = eqI[tid]; ckL[base0 + tid] = exactKey;
        }
      } else if (tid == 0) {
        // rare: surplus exact-key ties -> smallest original indices win (reference order)
        int base0 = kM - needed4; int lastI = -1;
        for (int q = 0; q < needed4; ++q) {
          int mv = INT_MAX;
          for (int x = 0; x < pc; ++x) {
            if (pk[x] == exactKey) { int ix = piA[x]; if (ix > lastI && ix < mv) mv = ix; }
          }
          ciL[base0 + q] = mv; ckL[base0 + q] = exactKey; lastI = mv;
        }
      }
      __syncthreads();
    } else {
      // pathological pool overflow (>4096 keys sharing 12-bit prefix): exact serial path
      if (tid == 0) {
        int base0 = sCnt;  // == cumAbove1
        unsigned lastK = 0xFFFFFFFFu; int lastI = INT_MAX;
        for (int q = 0; q < needed; ++q) {
          unsigned bk = 0u; int bi2 = -1;
          for (int x = 0; x < kN; ++x) {
            unsigned k = kk[x];
            if ((k >> 20) != uB) continue;
            if (k > lastK || (k == lastK && x <= lastI)) continue;  // already taken
            if (bi2 < 0 || k > bk || (k == bk && x < bi2)) { bk = k; bi2 = x; }
          }
          ciL[base0 + q] = bi2; ckL[base0 + q] = bk; lastK = bk; lastI = bi2;
        }
      }
      __syncthreads();
    }
  }

  // ================= NMS phase: wave 0 only, 4 candidates/lane, register state =========
  if (tid >= 64) return;
  int lane = tid;

  float x1[4], y1[4], x2[4], y2[4], val[4], s[4];
  int cls[4];
  bool kept[4];

  #pragma unroll
  for (int q = 0; q < 4; ++q) {
    int slot = q * 64 + lane;
    int n = ciL[slot];
    float sc = key_to_score(ckL[slot]);  // bit-exact score from kernel 1 (kNEG for filler)
    kept[q] = false;
    x1[q] = y1[q] = x2[q] = y2[q] = 0.f;
    cls[q] = 0; val[q] = sc; s[q] = sc;
    if (n >= 0) {
      int lvl, a, gi, gj; float stride;
      const float* p = cell_ptr(p0, p1, p2, b, n, lvl, a, gi, gj, stride);
      const float2* r2 = (const float2*)p;   // rows are 104 B: even-float offsets 8B-aligned
      float2 c01 = r2[0], c23 = r2[1];
      float cx = (fsigm(c01.x) + (float)gj) * stride;
      float cy = (fsigm(c01.y) + (float)gi) * stride;
      float w = fexpf(c23.x) * c_anchors[lvl][a][0];  // (exp*anc/stride)*stride == exp*anc
      float h = fexpf(c23.y) * c_anchors[lvl][a][1];
      x1[q] = fminf(fmaxf(cx - 0.5f * w, 0.f), 608.f);
      y1[q] = fminf(fmaxf(cy - 0.5f * h, 0.f), 608.f);
      x2[q] = fminf(fmaxf(cx + 0.5f * w, 0.f), 608.f);
      y2[q] = fminf(fmaxf(cy + 0.5f * h, 0.f), 608.f);
      float lm = -3.4e38f; int mc = 0;
      #pragma unroll
      for (int j = 3; j < 13; ++j) {
        float2 v = r2[j];
        int c0 = 2 * (j - 3);
        if (v.x > lm) { lm = v.x; mc = c0; }
        if (v.y > lm) { lm = v.y; mc = c0 + 1; }
      }
      cls[q] = mc;
    }
  }

  // top-8 kept ORIGINAL scores, maintained identically (uniformly) on all lanes
  float top8[8];
  #pragma unroll
  for (int i = 0; i < 8; ++i) top8[i] = kNEG;
  int keptCount = 0;

  for (int it = 0; it < kM; ++it) {
    float bv = s[0]; int bq = 0;
    #pragma unroll
    for (int q = 1; q < 4; ++q) if (s[q] > bv) { bv = s[q]; bq = q; }
    int bi = bq * 64 + lane;
    waveArgmax(bv, bi);
    if (bv < 0.1f) break;   // all remaining reference steps are no-ops -> exact

    int wlane = bi & 63, wq = bi >> 6;
    float jx1 = __shfl(sel4f(x1, wq), wlane);
    float jy1 = __shfl(sel4f(y1, wq), wlane);
    float jx2 = __shfl(sel4f(x2, wq), wlane);
    float jy2 = __shfl(sel4f(y2, wq), wlane);
    float jval = __shfl(sel4f(val, wq), wlane);
    int   cj  = __shfl(sel4i(cls, wq), wlane);

    float a1 = (jx2 - jx1 + 1.0f) * (jy2 - jy1 + 1.0f);
    #pragma unroll
    for (int q = 0; q < 4; ++q) {
      if (cls[q] == cj) {
        float ix1 = fmaxf(jx1, x1[q]), iy1 = fmaxf(jy1, y1[q]);
        float ix2 = fminf(jx2, x2[q]), iy2 = fminf(jy2, y2[q]);
        float inter = fmaxf(ix2 - ix1 + 1.0f, 0.0f) * fmaxf(iy2 - iy1 + 1.0f, 0.0f);
        float a2 = (x2[q] - x1[q] + 1.0f) * (y2[q] - y1[q] + 1.0f);
        float iou = inter / (a1 + a2 - inter + 1e-16f);
        s[q] *= fexpf(-(iou * iou) * 2.0f);
      }
      if (bi == q * 64 + lane) { kept[q] = true; s[q] = kNEG; }  // winner slot
    }

    // early-stop bookkeeping (uniform scalar work on every lane)
    float v = jval;
    #pragma unroll
    for (int i = 0; i < 8; ++i) { float m = fmaxf(top8[i], v); v = fminf(top8[i], v); top8[i] = m; }
    ++keptCount;
    if (keptCount >= kTopK) {
      float am = kNEG;
      #pragma unroll
      for (int q = 0; q < 4; ++q) if (s[q] >= 0.1f) am = fmaxf(am, val[q]);
      am = waveMax(am);
      // no alive candidate's ORIGINAL score can beat the 8th-best kept original:
      // s is monotone non-increasing, originals fixed, kept flags never revert -> exact stop
      if (am < top8[7]) break;
    }
  }

  // keep_top_k by ORIGINAL score among kept
  float f[4];
  #pragma unroll
  for (int q = 0; q < 4; ++q) f[q] = kept[q] ? val[q] : kNEG;
  for (int k = 0; k < kTopK; ++k) {
    float bv = f[0]; int bq = 0;
    #pragma unroll
    for (int q = 1; q < 4; ++q) if (f[q] > bv) { bv = f[q]; bq = q; }
    int bi = bq * 64 + lane;
    waveArgmax(bv, bi);
    int wlane = bi & 63, wq = bi >> 6;
    if (lane == wlane) {
      float* o = out + (size_t)(b * kTopK + k) * 6;
      if (bv > kNEG * 0.5f) {
        o[0] = sel4f(x1, wq); o[1] = sel4f(y1, wq);
        o[2] = sel4f(x2, wq); o[3] = sel4f(y2, wq);
        o[4] = sel4f(val, wq); o[5] = (float)sel4i(cls, wq);
      } else {
        o[0] = 0.f; o[1] = 0.f; o[2] = 0.f; o[3] = 0.f; o[4] = 0.f; o[5] = 0.f;
      }
    }
    #pragma unroll
    for (int q = 0; q < 4; ++q) if (bi == q * 64 + lane) f[q] = kNEG;
  }
}

// ---------------- host launch ----------------
extern "C" void kernel_launch(void* const* d_in, const int* in_sizes, int n_in,
                              void* d_out, int out_size, void* d_ws, size_t ws_size,
                              hipStream_t stream) {
  const float* p0 = (const float*)d_in[0];
  const float* p1 = (const float*)d_in[1];
  const float* p2 = (const float*)d_in[2];
  float* out = (float*)d_out;

  // workspace layout:
  //   keys  u32[kB*kNP]   5.82 MB (rows padded to 22744 for 16B alignment)
  //   gHist i32[kB*kHB]   1.00 MB (per-image 12-bit score histogram)
  unsigned* keys = (unsigned*)d_ws;
  int* gHist = (int*)((char*)d_ws + (size_t)kB * kNP * sizeof(unsigned));

  hipMemsetAsync(gHist, 0, (size_t)kB * kHB * sizeof(int), stream);
  score_kernel<<<kGridScore, 256, 0, stream>>>(p0, p1, p2, keys, gHist);
  select_nms_kernel<<<kB, 512, 0, stream>>>(keys, gHist, p0, p1, p2, out);
}

// Round 2
// 224.230 us; speedup vs baseline: 1.1653x; 1.1653x over previous
//
#include <hip/hip_runtime.h>
#include <climits>
#include <cstdint>

// ---------------- problem constants (mirror reference) ----------------
constexpr int kB  = 64;
constexpr int kG0 = 19, kG1 = 38, kG2 = 76;
constexpr int kN0 = 3 * kG0 * kG0;   // 1083
constexpr int kN1 = 3 * kG1 * kG1;   // 4332
constexpr int kN2 = 3 * kG2 * kG2;   // 17328
constexpr int kN  = kN0 + kN1 + kN2; // 22743
constexpr int kNP = kN + 1;          // padded row stride (22744): rows 16B-aligned for uint4
constexpr int kM  = 256;             // M_CAND
constexpr int kTopK = 8;
constexpr float kNEG = -1e9f;
constexpr int kHB = 4096;            // 12-bit score-histogram bins

// per-image tiles of 256 cells per level: ceil(1083/256)=5, ceil(4332/256)=17, ceil(17328/256)=68
constexpr int kT0 = 5, kT1 = 17, kT2 = 68;
constexpr int kTilesPerImg = kT0 + kT1 + kT2;  // 90
constexpr int kGridScore = kB * kTilesPerImg;  // 5760: ONE tile per block (occupancy > pipelining)

__constant__ float c_anchors[3][3][2] = {
    {{116.f, 90.f}, {156.f, 198.f}, {373.f, 326.f}},
    {{30.f, 61.f},  {62.f, 45.f},   {59.f, 119.f}},
    {{10.f, 13.f},  {16.f, 30.f},   {33.f, 23.f}},
};

typedef float f4_t __attribute__((ext_vector_type(4)));

// fast transcendentals: v_exp_f32 + v_rcp_f32 (~2-4 ULP; thresholds have huge slack)
__device__ __forceinline__ float fexpf(float x) { return __expf(x); }
__device__ __forceinline__ float frcpf(float x) { return __builtin_amdgcn_rcpf(x); }
__device__ __forceinline__ float fsigm(float x) { return frcpf(1.0f + __expf(-x)); }

// non-temporal loads (no cache allocation -> doesn't evict the harness's dirty
// poison lines from L3; still HITS L3/L2 when the line is already resident)
__device__ __forceinline__ float2 nt_load_f2(const float2* p) {
  unsigned long long v = __builtin_nontemporal_load((const unsigned long long*)p);
  union { unsigned long long u; float2 f; } c; c.u = v; return c.f;
}
__device__ __forceinline__ f4_t nt_load_f4(const f4_t* p) {
  return __builtin_nontemporal_load(p);
}

// order-preserving float->uint key (ascending). NEG maps below every score>=0.
__device__ __forceinline__ unsigned score_to_key(float s) {
  unsigned fb = __float_as_uint(s);
  unsigned m = (fb & 0x80000000u) ? 0xFFFFFFFFu : 0x80000000u;
  return fb ^ m;
}
__device__ __forceinline__ float key_to_score(unsigned k) {
  unsigned fb = (k & 0x80000000u) ? (k ^ 0x80000000u) : ~k;
  return __uint_as_float(fb);
}

// flat candidate index n -> cell pointer + (level, anchor, row i, col j, stride)
__device__ __forceinline__ const float* cell_ptr(
    const float* p0, const float* p1, const float* p2, int b, int n,
    int& lvl, int& a, int& gi, int& gj, float& stride) {
  const float* src; int G, m;
  if (n < kN0)            { src = p0; G = kG0; lvl = 0; m = n;             stride = 32.f; }
  else if (n < kN0 + kN1) { src = p1; G = kG1; lvl = 1; m = n - kN0;       stride = 16.f; }
  else                    { src = p2; G = kG2; lvl = 2; m = n - kN0 - kN1; stride = 8.f; }
  int gg = G * G;
  a = m / gg;
  int r = m - a * gg;
  gi = r / G;
  gj = r - gi * G;
  return src + (size_t)((((b * 3 + a) * G + gi) * G + gj)) * 26;
}

// ---------------- wave (64-lane) helpers ----------------
__device__ __forceinline__ void waveArgmax(float& v, int& i) {
  #pragma unroll
  for (int off = 1; off < 64; off <<= 1) {
    float ov = __shfl_xor(v, off);
    int oi = __shfl_xor(i, off);
    if (ov > v || (ov == v && oi < i)) { v = ov; i = oi; }
  }
}
__device__ __forceinline__ float waveMax(float v) {
  #pragma unroll
  for (int off = 1; off < 64; off <<= 1) v = fmaxf(v, __shfl_xor(v, off));
  return v;
}
__device__ __forceinline__ float sel4f(const float a[4], int q) {
  float r = a[0];
  r = (q == 1) ? a[1] : r;
  r = (q == 2) ? a[2] : r;
  r = (q == 3) ? a[3] : r;
  return r;
}
__device__ __forceinline__ int sel4i(const int a[4], int q) {
  int r = a[0];
  r = (q == 1) ? a[1] : r;
  r = (q == 2) ? a[2] : r;
  r = (q == 3) ? a[3] : r;
  return r;
}

// ---------------- kernel 1: one 256-cell tile per block, single-buffer LDS ------------
// Round-1 counters showed the double-buffered 3-tile pipeline was latency-bound at 24%
// occupancy (2 blocks/CU from 53 KB LDS), with VALU 10% and HBM 15%. Single 26 KB buffer
// -> 6 blocks/CU (24 waves, 75%): latency hiding via inter-block TLP instead.
// Staging: NT dwordx4 (16 B/lane) where the tile base is 16B-aligned (94.5% of bytes,
// all tiles except level-0 tiles of odd images); NT float2 fallback otherwise.
__global__ __launch_bounds__(256) void score_kernel(
    const float* __restrict__ p0, const float* __restrict__ p1, const float* __restrict__ p2,
    unsigned* __restrict__ keys)
{
  __shared__ float lds[256 * 26];   // 26624 B -> 6 blocks/CU

  int t = threadIdx.x;
  int tileId = (int)blockIdx.x;
  int b = tileId / kTilesPerImg;
  int r = tileId - b * kTilesPerImg;
  const float* slab; int NL, lvlOff, tile;
  if (r < kT0)            { slab = p0; NL = kN0; lvlOff = 0;         tile = r; }
  else if (r < kT0 + kT1) { slab = p1; NL = kN1; lvlOff = kN0;       tile = r - kT0; }
  else                    { slab = p2; NL = kN2; lvlOff = kN0 + kN1; tile = r - kT0 - kT1; }
  int cellBase = tile * 256;
  int nc = min(256, NL - cellBase);
  const float* g = slab + ((size_t)b * NL + cellBase) * 26;
  int nf = nc * 26;

  if ((((uintptr_t)g) & 15) == 0) {
    int n4 = nf >> 2;
    f4_t* d4 = (f4_t*)lds;
    #pragma unroll
    for (int k = 0; k < 7; ++k) {
      int i = t + k * 256;
      if (i < n4) d4[i] = nt_load_f4((const f4_t*)g + i);
    }
    if ((nf & 3) && t == 0) {         // 2-dword tail (odd cell-count tiles)
      ((float2*)lds)[n4 << 1] = nt_load_f2((const float2*)g + (n4 << 1));
    }
  } else {
    int n2 = nf >> 1;                 // nf always even
    float2* d2 = (float2*)lds;
    #pragma unroll
    for (int k = 0; k < 13; ++k) {
      int i = t + k * 256;
      if (i < n2) d2[i] = nt_load_f2((const float2*)g + i);
    }
  }
  __syncthreads();

  if (t < nc) {
    const float2* c2 = (const float2*)&lds[t * 26];  // stride-26: 2-way bank alias (free)
    float2 ol = c2[2];                // channels 4,5
    float obj = fsigm(ol.x);
    float loc = fsigm(ol.y);
    float tch[20];
    #pragma unroll
    for (int q = 0; q < 10; ++q) { float2 v = c2[3 + q]; tch[2*q] = v.x; tch[2*q+1] = v.y; }
    float lm = tch[0];
    #pragma unroll
    for (int c = 1; c < 20; ++c) lm = fmaxf(lm, tch[c]);
    float se = 0.f;
    #pragma unroll
    for (int c = 0; c < 20; ++c) se += fexpf(tch[c] - lm);
    float cls_conf = frcpf(se);       // max of softmax == exp(0)/sum
    float conf = obj * cls_conf;
    float masked = (obj >= 0.6f && loc >= 0.5f && conf >= 0.05f)
                   ? sqrtf(conf) * sqrtf(loc) : kNEG;  // (obj*cc)^.5 * loc^.5
    keys[(size_t)b * kNP + lvlOff + cellBase + t] = score_to_key(masked);  // coalesced
  }
}

// ---------------- parallel threshold-bin finder ----------------
// Largest bin B with suffix_count(B) >= needed; cumAbove = count strictly above B; total = all.
// All 512 threads participate uniformly.
__device__ __forceinline__ void findThresholdBin(
    const int* hist, int NB, int needed,
    int& outB, int& outCumAbove, int& outTotal,
    int* shWave, int* shOut)
{
  int tid = threadIdx.x, lane = tid & 63, w = tid >> 6;
  if (tid == 0) { shOut[0] = -1; shOut[1] = 0; }
  int ipt = (NB + 511) / 512;
  int base = tid * ipt;
  int csum = 0;
  for (int i = 0; i < ipt; ++i) { int bn = base + i; if (bn < NB) csum += hist[bn]; }
  // inclusive suffix scan within wave (lane l gets sum over lanes >= l)
  int v = csum;
  #pragma unroll
  for (int off = 1; off < 64; off <<= 1) {
    int tv = __shfl_down(v, off);
    if (lane + off < 64) v += tv;
  }
  if (lane == 0) shWave[w] = v;   // wave total
  __syncthreads();
  int above = 0, total = 0;
  #pragma unroll
  for (int q = 0; q < 8; ++q) {
    int wt = shWave[q];
    total += wt;
    if (q > w) above += wt;
  }
  int S = v + above;              // suffix count including own chunk
  if (S >= needed && S - csum < needed) {   // exactly one thread's chunk crosses
    int running = S - csum;
    for (int i = ipt - 1; i >= 0; --i) {
      int bn = base + i; if (bn >= NB) continue;
      int c = hist[bn];
      if (running + c >= needed) { shOut[0] = bn; shOut[1] = running; break; }
      running += c;
    }
  }
  __syncthreads();
  outB = shOut[0]; outCumAbove = shOut[1]; outTotal = total;
  __syncthreads();
}

constexpr int kNV4 = kN / 4;        // 5685 full uint4 per image row (covers 22740)
constexpr int kTail = kN - kNV4*4;  // 3 scalar tail elements

// ---------------- kernel 2: two-sweep select + soft-NMS (wave 0) ----------------------
// Sweep 1 builds the 12-bit histogram (keys row is 91 KB, L2/L3-resident after kernel 1 ->
// near-free). Sweep 2 gathers winners (>bin) and pools bin ties in LDS; tie refinement
// (key bits 19:8, 7:0, then smallest index) runs entirely on the LDS pool. Then wave 0
// runs the register-resident NMS. Candidate set + scores bit-identical to the 4-sweep
// round-0 version. No global atomics, no extra dispatches.
__global__ __launch_bounds__(512) void select_nms_kernel(
    const unsigned* __restrict__ keys,
    const float* __restrict__ p0, const float* __restrict__ p1, const float* __restrict__ p2,
    float* __restrict__ out)
{
  int b = blockIdx.x, tid = threadIdx.x;
  const unsigned* kk = keys + (size_t)b * kNP;
  const uint4* kk4 = (const uint4*)kk;      // row base b*kNP*4 = b*90976 (16-aligned)
  const unsigned keyNEG = score_to_key(kNEG);

  constexpr int kPool = 4096;
  __shared__ int hist[kHB];                 // pass-1 hist, then reused as mid/low hist
  __shared__ int shWave[8], shOut[2];
  __shared__ int ciL[kM];
  __shared__ unsigned ckL[kM];
  __shared__ unsigned pk[kPool];            // bin-B tie pool: keys
  __shared__ int piA[kPool];                //                 original indices
  __shared__ int eqI[256];                  // exact-key tie indices (fast path)
  __shared__ int sCnt, eqCnt, sTie;

  // ---- sweep 1: top-12-bit histogram (skip NEG keys) ----
  for (int i = tid; i < kHB; i += 512) hist[i] = 0;
  __syncthreads();
  for (int x = tid; x < kNV4; x += 512) {
    uint4 v = kk4[x];
    if (v.x >= 0x80000000u) atomicAdd(&hist[v.x >> 20], 1);
    if (v.y >= 0x80000000u) atomicAdd(&hist[v.y >> 20], 1);
    if (v.z >= 0x80000000u) atomicAdd(&hist[v.z >> 20], 1);
    if (v.w >= 0x80000000u) atomicAdd(&hist[v.w >> 20], 1);
  }
  if (tid < kTail) {
    unsigned k = kk[kNV4 * 4 + tid];
    if (k >= 0x80000000u) atomicAdd(&hist[k >> 20], 1);
  }
  __syncthreads();
  int B, cumAbove1, total1;
  findThresholdBin(hist, kHB, kM, B, cumAbove1, total1, shWave, shOut);

  if (tid == 0) { sCnt = 0; eqCnt = 0; sTie = 0; }
  // re-zero for the mid-bits histogram built during sweep 2
  for (int i = tid; i < kHB; i += 512) hist[i] = 0;
  __syncthreads();

  if (total1 < kM) {
    // ---- fewer than 256 valid: gather them all, pad with dummies ----
    for (int x = tid; x < kNV4; x += 512) {
      uint4 v = kk4[x];
      int i4 = x * 4;
      unsigned kv[4] = {v.x, v.y, v.z, v.w};
      #pragma unroll
      for (int e = 0; e < 4; ++e) {
        unsigned k = kv[e];
        if (k & 0x80000000u) { int p = atomicAdd(&sCnt, 1); ciL[p] = i4 + e; ckL[p] = k; }
      }
    }
    if (tid < kTail) {
      int x = kNV4 * 4 + tid;
      unsigned k = kk[x];
      if (k & 0x80000000u) { int p = atomicAdd(&sCnt, 1); ciL[p] = x; ckL[p] = k; }
    }
    __syncthreads();
    // NEG filler candidates: never kept, never picked, never influence others
    if (tid >= total1 && tid < kM) { ciL[tid] = -1; ckL[tid] = keyNEG; }
    __syncthreads();
  } else {
    unsigned uB = (unsigned)B;
    // ---- sweep 2: gather hi>B winners; pool hi==B ties (+build mid-hist) ----
    for (int x = tid; x < kNV4; x += 512) {
      uint4 v = kk4[x];
      int i4 = x * 4;
      unsigned kv[4] = {v.x, v.y, v.z, v.w};
      #pragma unroll
      for (int e = 0; e < 4; ++e) {
        unsigned k = kv[e];
        unsigned hi = k >> 20;
        if (hi > uB) { int p = atomicAdd(&sCnt, 1); ciL[p] = i4 + e; ckL[p] = k; }
        else if (hi == uB) {
          int p = atomicAdd(&eqCnt, 1);
          if (p < kPool) { pk[p] = k; piA[p] = i4 + e; }
          atomicAdd(&hist[(k >> 8) & 0xFFFu], 1);
        }
      }
    }
    if (tid < kTail) {
      int x = kNV4 * 4 + tid;
      unsigned k = kk[x];
      unsigned hi = k >> 20;
      if (hi > uB) { int p = atomicAdd(&sCnt, 1); ciL[p] = x; ckL[p] = k; }
      else if (hi == uB) {
        int p = atomicAdd(&eqCnt, 1);
        if (p < kPool) { pk[p] = k; piA[p] = x; }
        atomicAdd(&hist[(k >> 8) & 0xFFFu], 1);
      }
    }
    __syncthreads();

    int needed = kM - cumAbove1;   // >= 1 by construction; sCnt == cumAbove1 here
    int pc = eqCnt;                // == exact bin-B population even if pool overflowed

    if (pc == needed) {
      // common-ish shortcut: whole bin fits exactly (pc <= 255 < kPool always here)
      if (tid < pc) { ciL[cumAbove1 + tid] = piA[tid]; ckL[cumAbove1 + tid] = pk[tid]; }
      __syncthreads();
    } else if (pc <= kPool) {
      // ---- LDS-resident refinement: bits 19:8, then 7:0, then smallest index ----
      int B2, cA2, tot2;
      findThresholdBin(hist, kHB, needed, B2, cA2, tot2, shWave, shOut);
      for (int i = tid; i < 256; i += 512) hist[i] = 0;   // reuse as low-8 hist
      __syncthreads();
      for (int i = tid; i < pc; i += 512) {
        unsigned k = pk[i];
        int mid = (int)((k >> 8) & 0xFFFu);
        if (mid > B2) { int p = atomicAdd(&sCnt, 1); ciL[p] = piA[i]; ckL[p] = k; }
        else if (mid == B2) atomicAdd(&hist[k & 0xFFu], 1);
      }
      __syncthreads();
      int needed3 = needed - cA2;
      int B3, cA3, tot3;
      findThresholdBin(hist, 256, needed3, B3, cA3, tot3, shWave, shOut);
      for (int i = tid; i < pc; i += 512) {
        unsigned k = pk[i];
        int mid = (int)((k >> 8) & 0xFFFu);
        if (mid == B2) {
          int lo = (int)(k & 0xFFu);
          if (lo > B3) { int p = atomicAdd(&sCnt, 1); ciL[p] = piA[i]; ckL[p] = k; }
          else if (lo == B3) { int p = atomicAdd(&sTie, 1); if (p < 256) eqI[p] = piA[i]; }
        }
      }
      __syncthreads();
      int needed4 = needed3 - cA3;   // >= 1
      unsigned exactKey = (uB << 20) | ((unsigned)B2 << 8) | (unsigned)B3;
      int nt_ = sTie;
      if (nt_ == needed4) {
        // typical: exact-threshold key unique (or exactly fills) -> direct append
        if (tid < needed4) {
          int base0 = kM - needed4;
          ciL[base0 + tid] = eqI[tid]; ckL[base0 + tid] = exactKey;
        }
      } else if (tid == 0) {
        // rare: surplus exact-key ties -> smallest original indices win (reference order)
        int base0 = kM - needed4; int lastI = -1;
        for (int q = 0; q < needed4; ++q) {
          int mv = INT_MAX;
          for (int x = 0; x < pc; ++x) {
            if (pk[x] == exactKey) { int ix = piA[x]; if (ix > lastI && ix < mv) mv = ix; }
          }
          ciL[base0 + q] = mv; ckL[base0 + q] = exactKey; lastI = mv;
        }
      }
      __syncthreads();
    } else {
      // pathological pool overflow (>4096 keys sharing 12-bit prefix): exact serial path
      if (tid == 0) {
        int base0 = sCnt;  // == cumAbove1
        unsigned lastK = 0xFFFFFFFFu; int lastI = INT_MAX;
        for (int q = 0; q < needed; ++q) {
          unsigned bk = 0u; int bi2 = -1;
          for (int x = 0; x < kN; ++x) {
            unsigned k = kk[x];
            if ((k >> 20) != uB) continue;
            if (k > lastK || (k == lastK && x <= lastI)) continue;  // already taken
            if (bi2 < 0 || k > bk || (k == bk && x < bi2)) { bk = k; bi2 = x; }
          }
          ciL[base0 + q] = bi2; ckL[base0 + q] = bk; lastK = bk; lastI = bi2;
        }
      }
      __syncthreads();
    }
  }

  // ================= NMS phase: wave 0 only, 4 candidates/lane, register state =========
  if (tid >= 64) return;
  int lane = tid;

  float x1[4], y1[4], x2[4], y2[4], val[4], s[4];
  int cls[4];
  bool kept[4];

  #pragma unroll
  for (int q = 0; q < 4; ++q) {
    int slot = q * 64 + lane;
    int n = ciL[slot];
    float sc = key_to_score(ckL[slot]);  // bit-exact score from kernel 1 (kNEG for filler)
    kept[q] = false;
    x1[q] = y1[q] = x2[q] = y2[q] = 0.f;
    cls[q] = 0; val[q] = sc; s[q] = sc;
    if (n >= 0) {
      int lvl, a, gi, gj; float stride;
      const float* p = cell_ptr(p0, p1, p2, b, n, lvl, a, gi, gj, stride);
      const float2* r2 = (const float2*)p;   // rows are 104 B: even-float offsets 8B-aligned
      float2 c01 = r2[0], c23 = r2[1];
      float cx = (fsigm(c01.x) + (float)gj) * stride;
      float cy = (fsigm(c01.y) + (float)gi) * stride;
      float w = fexpf(c23.x) * c_anchors[lvl][a][0];  // (exp*anc/stride)*stride == exp*anc
      float h = fexpf(c23.y) * c_anchors[lvl][a][1];
      x1[q] = fminf(fmaxf(cx - 0.5f * w, 0.f), 608.f);
      y1[q] = fminf(fmaxf(cy - 0.5f * h, 0.f), 608.f);
      x2[q] = fminf(fmaxf(cx + 0.5f * w, 0.f), 608.f);
      y2[q] = fminf(fmaxf(cy + 0.5f * h, 0.f), 608.f);
      float lm = -3.4e38f; int mc = 0;
      #pragma unroll
      for (int j = 3; j < 13; ++j) {
        float2 v = r2[j];
        int c0 = 2 * (j - 3);
        if (v.x > lm) { lm = v.x; mc = c0; }
        if (v.y > lm) { lm = v.y; mc = c0 + 1; }
      }
      cls[q] = mc;
    }
  }

  // top-8 kept ORIGINAL scores, maintained identically (uniformly) on all lanes
  float top8[8];
  #pragma unroll
  for (int i = 0; i < 8; ++i) top8[i] = kNEG;
  int keptCount = 0;

  for (int it = 0; it < kM; ++it) {
    float bv = s[0]; int bq = 0;
    #pragma unroll
    for (int q = 1; q < 4; ++q) if (s[q] > bv) { bv = s[q]; bq = q; }
    int bi = bq * 64 + lane;
    waveArgmax(bv, bi);
    if (bv < 0.1f) break;   // all remaining reference steps are no-ops -> exact

    int wlane = bi & 63, wq = bi >> 6;
    float jx1 = __shfl(sel4f(x1, wq), wlane);
    float jy1 = __shfl(sel4f(y1, wq), wlane);
    float jx2 = __shfl(sel4f(x2, wq), wlane);
    float jy2 = __shfl(sel4f(y2, wq), wlane);
    float jval = __shfl(sel4f(val, wq), wlane);
    int   cj  = __shfl(sel4i(cls, wq), wlane);

    float a1 = (jx2 - jx1 + 1.0f) * (jy2 - jy1 + 1.0f);
    #pragma unroll
    for (int q = 0; q < 4; ++q) {
      if (cls[q] == cj) {
        float ix1 = fmaxf(jx1, x1[q]), iy1 = fmaxf(jy1, y1[q]);
        float ix2 = fminf(jx2, x2[q]), iy2 = fminf(jy2, y2[q]);
        float inter = fmaxf(ix2 - ix1 + 1.0f, 0.0f) * fmaxf(iy2 - iy1 + 1.0f, 0.0f);
        float a2 = (x2[q] - x1[q] + 1.0f) * (y2[q] - y1[q] + 1.0f);
        float iou = inter / (a1 + a2 - inter + 1e-16f);
        s[q] *= fexpf(-(iou * iou) * 2.0f);
      }
      if (bi == q * 64 + lane) { kept[q] = true; s[q] = kNEG; }  // winner slot
    }

    // early-stop bookkeeping (uniform scalar work on every lane)
    float v = jval;
    #pragma unroll
    for (int i = 0; i < 8; ++i) { float m = fmaxf(top8[i], v); v = fminf(top8[i], v); top8[i] = m; }
    ++keptCount;
    if (keptCount >= kTopK) {
      float am = kNEG;
      #pragma unroll
      for (int q = 0; q < 4; ++q) if (s[q] >= 0.1f) am = fmaxf(am, val[q]);
      am = waveMax(am);
      // no alive candidate's ORIGINAL score can beat the 8th-best kept original:
      // s is monotone non-increasing, originals fixed, kept flags never revert -> exact stop
      if (am < top8[7]) break;
    }
  }

  // keep_top_k by ORIGINAL score among kept
  float f[4];
  #pragma unroll
  for (int q = 0; q < 4; ++q) f[q] = kept[q] ? val[q] : kNEG;
  for (int k = 0; k < kTopK; ++k) {
    float bv = f[0]; int bq = 0;
    #pragma unroll
    for (int q = 1; q < 4; ++q) if (f[q] > bv) { bv = f[q]; bq = q; }
    int bi = bq * 64 + lane;
    waveArgmax(bv, bi);
    int wlane = bi & 63, wq = bi >> 6;
    if (lane == wlane) {
      float* o = out + (size_t)(b * kTopK + k) * 6;
      if (bv > kNEG * 0.5f) {
        o[0] = sel4f(x1, wq); o[1] = sel4f(y1, wq);
        o[2] = sel4f(x2, wq); o[3] = sel4f(y2, wq);
        o[4] = sel4f(val, wq); o[5] = (float)sel4i(cls, wq);
      } else {
        o[0] = 0.f; o[1] = 0.f; o[2] = 0.f; o[3] = 0.f; o[4] = 0.f; o[5] = 0.f;
      }
    }
    #pragma unroll
    for (int q = 0; q < 4; ++q) if (bi == q * 64 + lane) f[q] = kNEG;
  }
}

// ---------------- host launch ----------------
extern "C" void kernel_launch(void* const* d_in, const int* in_sizes, int n_in,
                              void* d_out, int out_size, void* d_ws, size_t ws_size,
                              hipStream_t stream) {
  const float* p0 = (const float*)d_in[0];
  const float* p1 = (const float*)d_in[1];
  const float* p2 = (const float*)d_in[2];
  float* out = (float*)d_out;

  // workspace layout: keys u32[kB*kNP] (5.82 MB; rows padded to 22744 for 16B alignment)
  unsigned* keys = (unsigned*)d_ws;

  score_kernel<<<kGridScore, 256, 0, stream>>>(p0, p1, p2, keys);
  select_nms_kernel<<<kB, 512, 0, stream>>>(keys, p0, p1, p2, out);
}